// Round 1
// baseline (192.112 us; speedup 1.0000x reference)
//
#include <hip/hip_runtime.h>

// dense_image_warp R8: column-persistent blocks + 128-row sliding-window LDS
// ring + counted-vmcnt pipelining (T3/T4).
//
// R7 was latency-bound (all pipes <30%): per-block issue -> __syncthreads()
// (vmcnt(0) drain) -> compute exposed the full 50KB window transfer once per
// block. R8: each of 256 blocks (1/CU, b=blk&7 keeps XCD=batch) walks a
// 32-tile column of 32x24 px. LDS holds a 4-band ring (128 rows x 64 cols x 3
// fp32, slot = row&127). Per iter: stage ONLY the 32 new rows of band t+2
// (2 global_load_lds/wave, uniform) + prefetch next tile's flow, then
// s_waitcnt vmcnt(3) + raw s_barrier -- this iteration's 3 vmem ops stay in
// flight across the barrier, so stage latency hides under compute. Vertical
// halo restaging is gone: staged image bytes 306 MB -> 214 MB.

constexpr int B = 8;
constexpr int H = 1024;
constexpr int W = 768;
constexpr int C = 3;

constexpr int TY = 32;
constexpr int TX = 24;
constexpr int TILES_Y = H / TY;          // 32 tiles down a column
constexpr int COLS_X  = W / TX;          // 32 columns/batch -> grid 256 = #CUs

constexpr int WIN_COLS = 64;             // staged slice: cols [X0-20, X0+43]
constexpr int WSF = WIN_COLS * C;        // 192 floats = 768 B per ring row
constexpr int ROW_CHUNKS = WSF / 4;      // 48 x 16B chunks per row
constexpr int BAND = TY;                 // 32 rows per band
constexpr int RING_ROWS = 4 * BAND;      // 128 -> lds row = image row & 127
constexpr int BAND_GROUPS = BAND * ROW_CHUNKS / 64;   // 24 wave-groups/band
constexpr int NTHREADS = TY * TX;        // 768 threads = 12 waves
constexpr int NWAVES = NTHREADS / 64;    // 12
constexpr int GPW = BAND_GROUPS / NWAVES;// 2 global_load_lds / wave / band

static_assert(GPW * NWAVES == BAND_GROUPS, "uniform staging required for vmcnt");

typedef float vfloat2 __attribute__((ext_vector_type(2)));
typedef float vfloat4 __attribute__((ext_vector_type(4)));
typedef float vfloat2_a4 __attribute__((ext_vector_type(2), aligned(4)));
typedef float vfloat4_a4 __attribute__((ext_vector_type(4), aligned(4)));

__global__ __launch_bounds__(NTHREADS) void warp_kernel(
    const float* __restrict__ image,   // [B,H,W,3]
    const float* __restrict__ flow,    // [B,H,W,2]
    float* __restrict__ out)           // [B,H,W,3]
{
    __shared__ float win[RING_ROWS * WSF];   // 98304 B -> 1 block/CU

    const int b  = blockIdx.x & 7;           // XCD = batch
    const int tx = blockIdx.x >> 3;          // column 0..31
    const int X0 = tx * TX;
    const int colLo = min(max(X0 - 20, 0), W - WIN_COLS);   // mult of 4

    const int lane = threadIdx.x & 63;
    const int wv   = threadIdx.x >> 6;       // 0..11

    const int py  = threadIdx.x / TX;        // 0..31 (hoisted, const per thread)
    const int pxx = threadIdx.x - py * TX;   // 0..23
    const int xg  = X0 + pxx;
    const float xgf = (float)xg;

    const float* gcol = image + (size_t)b * H * (W * C) + colLo * C;

    // stage one 32-row band (absolute band index k); rows clamped to H-1.
    // Band is LINEAR in LDS (slot base + j*1024B + lane*16B) -> valid
    // global_load_lds dest; global source is per-lane (allowed).
    auto stage_band = [&](int k) {
        const int slotBase = (k & 3) * BAND;
#pragma unroll
        for (int i = 0; i < GPW; ++i) {
            const int j  = i * NWAVES + wv;       // 0..23, wave-uniform
            const int ci = j * 64 + lane;         // chunk in band
            const int r  = ci / ROW_CHUNKS;       // row in band
            const int c  = ci - r * ROW_CHUNKS;   // 16B chunk in row
            const int rimg = min(k * BAND + r, H - 1);
            const float* g = gcol + (size_t)rimg * (W * C) + c * 4;
            __builtin_amdgcn_global_load_lds(
                (const __attribute__((address_space(1))) void*)g,
                (__attribute__((address_space(3))) void*)(win + slotBase * WSF + j * 256),
                16, 0, 0);
        }
    };

    auto load_flow = [&](int t) -> vfloat2 {      // row-clamped for t==TILES_Y
        const int yf = min(t * TY + py, H - 1);
        return __builtin_nontemporal_load(
            (const vfloat2*)flow + (((size_t)b * H + yf) * W + xg));
    };

    // prologue: bands 0,1 (rows 0..63) + flow(0). Drained by iter 0's vmcnt(3).
    stage_band(0);
    stage_band(1);
    vfloat2 fcur = load_flow(0);

#pragma unroll 1
    for (int t = 0; t < TILES_Y; ++t) {
        stage_band(t + 2);                        // 2 loads -> dead slot (t-2)&3
        const vfloat2 fnxt = load_flow(t + 1);    // 1 load

        // counted wait: leave exactly this iter's 3 vmem ops in flight;
        // retires band t+1 (+ flow t) so compute below may read it.
        asm volatile("s_waitcnt vmcnt(3)" ::: "memory");
        __builtin_amdgcn_s_barrier();
        __builtin_amdgcn_sched_barrier(0);

        const int Y0 = t * TY;
        const int y  = Y0 + py;

        const float qy = (float)y - fcur.x;
        const float qx = xgf      - fcur.y;

        float y0f = floorf(qy);
        float x0f = floorf(qx);
        y0f = fminf(fmaxf(y0f, 0.0f), (float)(H - 2));
        x0f = fminf(fmaxf(x0f, 0.0f), (float)(W - 2));
        const float ay = fminf(fmaxf(qy - y0f, 0.0f), 1.0f);
        const float ax = fminf(fmaxf(qx - x0f, 0.0f), 1.0f);
        const int y0 = (int)y0f;
        const int x0 = (int)x0f;

        float tl0, tl1, tl2, tr0, tr1, tr2, bl0, bl1, bl2, br0, br1, br2;

        // resident-and-landed rows: bands t-1,t,t+1 = [Y0-32, Y0+64)
        const bool inwin = (y0 >= Y0 - BAND) & (y0 <= Y0 + 2 * BAND - 2) &
                           (x0 >= colLo) & (x0 <= colLo + WIN_COLS - 2);
        if (inwin) {
            const float* tp = &win[(y0 & (RING_ROWS - 1)) * WSF + (x0 - colLo) * C];
            const float* bp = &win[((y0 + 1) & (RING_ROWS - 1)) * WSF + (x0 - colLo) * C];
            tl0 = tp[0]; tl1 = tp[1]; tl2 = tp[2];
            tr0 = tp[3]; tr1 = tp[4]; tr2 = tp[5];
            bl0 = bp[0]; bl1 = bp[1]; bl2 = bp[2];
            br0 = bp[3]; br1 = bp[4]; br2 = bp[5];
        } else {
            // rare (~0.15% px): flow beyond halo -> direct global bilinear
            const float* top = image + (((size_t)b * H + y0) * W + x0) * C;
            const float* bot = top + (size_t)W * C;
            const vfloat4 t4 = *(const vfloat4_a4*)top;
            const vfloat2 t2 = *(const vfloat2_a4*)(top + 4);
            const vfloat4 b4 = *(const vfloat4_a4*)bot;
            const vfloat2 b2 = *(const vfloat2_a4*)(bot + 4);
            tl0 = t4.x; tl1 = t4.y; tl2 = t4.z;
            tr0 = t4.w; tr1 = t2.x; tr2 = t2.y;
            bl0 = b4.x; bl1 = b4.y; bl2 = b4.z;
            br0 = b4.w; br1 = b2.x; br2 = b2.y;
        }

        const float tp0 = tl0 + ax * (tr0 - tl0);
        const float tp1 = tl1 + ax * (tr1 - tl1);
        const float tp2 = tl2 + ax * (tr2 - tl2);
        const float bo0 = bl0 + ax * (br0 - bl0);
        const float bo1 = bl1 + ax * (br1 - bl1);
        const float bo2 = bl2 + ax * (br2 - bl2);

        float* o = out + (((size_t)b * H + y) * W + xg) * C;
        __builtin_nontemporal_store(tp0 + ay * (bo0 - tp0), &o[0]);
        __builtin_nontemporal_store(tp1 + ay * (bo1 - tp1), &o[1]);
        __builtin_nontemporal_store(tp2 + ay * (bo2 - tp2), &o[2]);

        // protect slot (t+3)&3 (= band t-1, still read above) from next
        // iteration's staging until all waves finish this tile.
        __builtin_amdgcn_s_barrier();
        __builtin_amdgcn_sched_barrier(0);
        fcur = fnxt;
    }
}

extern "C" void kernel_launch(void* const* d_in, const int* in_sizes, int n_in,
                              void* d_out, int out_size, void* d_ws, size_t ws_size,
                              hipStream_t stream) {
    const float* image = (const float*)d_in[0];
    const float* flow  = (const float*)d_in[1];
    float* out = (float*)d_out;

    dim3 grid(B * COLS_X);    // 256 blocks, 1 per CU
    dim3 block(NTHREADS);     // 768 threads = 12 waves
    warp_kernel<<<grid, block, 0, stream>>>(image, flow, out);
}

// Round 2
// 177.204 us; speedup vs baseline: 1.0841x; 1.0841x over previous
//
#include <hip/hip_runtime.h>

// dense_image_warp R9: R7 structure (stage window -> vmcnt(0)+barrier ->
// LDS gathers), scaled for max occupancy.
//
// R8 post-mortem: counted-vmcnt persistent ring REGRESSED (60.5 -> 73 us)
// because occupancy fell 52% -> 31%. Compute per px is tiny; resident-wave
// count is the controlling variable. R9 therefore maximizes the occupancy
// cap: 64x32 tile, 1024 threads (16 waves), 97x64 window @ 76.8 KB LDS ->
// 2 blocks/CU x 16 waves = 32 waves/CU (HW cap; R7 was 24). Halo amortizes
// 2x better (staged bytes 306 -> 230 MB). Row stride padded 192 -> 196
// floats (784 B = 49 x 16B chunks, still chunk-linear for global_load_lds;
// pad chunk never read) so jittered-row gathers stop hitting one bank
// (row stride mod 32 banks: 0 -> 4). TX=32 restores 64B-aligned col seams
// (R8's TX=24 inflated WRITE_SIZE 74 -> 85 MB).

constexpr int B = 8;
constexpr int H = 1024;
constexpr int W = 768;
constexpr int C = 3;

constexpr int TY = 64, TX = 32;          // output tile
constexpr int WIN_ROWS = 97;             // TY + 16 up + 16 down + 1
constexpr int WIN_COLS = 64;             // TX + ~16 halo each side
constexpr int ROW_CHUNKS = 49;           // 48 data chunks (192 fl) + 1 pad
constexpr int WSF = ROW_CHUNKS * 4;      // 196 floats row stride (784 B)
constexpr int CHUNKS = WIN_ROWS * ROW_CHUNKS;    // 4753 x 16B chunks
constexpr int TILES_X = W / TX;          // 24
constexpr int TILES_Y = H / TY;          // 16
constexpr int TILES_PER_B = TILES_X * TILES_Y;   // 384

constexpr int NTHREADS = 1024;           // 16 waves/block
constexpr int NWAVES = NTHREADS / 64;
constexpr int PX_PER_T = (TY * TX) / NTHREADS;   // 2

typedef float vfloat2 __attribute__((ext_vector_type(2)));
typedef float vfloat4 __attribute__((ext_vector_type(4)));
typedef float vfloat2_a4 __attribute__((ext_vector_type(2), aligned(4)));
typedef float vfloat4_a4 __attribute__((ext_vector_type(4), aligned(4)));

__global__ __launch_bounds__(NTHREADS, 8) void warp_kernel(
    const float* __restrict__ image,   // [B,H,W,3]
    const float* __restrict__ flow,    // [B,H,W,2]
    float* __restrict__ out)           // [B,H,W,3]
{
    // +192 floats: clamped tail lanes of the last staging issues land here
    __shared__ float win[WIN_ROWS * WSF + 192];   // 76816 B -> 2 blocks/CU

    // ---- XCD-aware decomposition: blockIdx%8 = XCD = batch ----
    const int flat = blockIdx.x;            // 0..3071
    const int b    = flat & 7;
    const int s    = flat >> 3;             // 0..383 temporal order in XCD
    const int ty   = s / TILES_X;
    const int tx   = s - ty * TILES_X;
    const int Y0 = ty * TY, X0 = tx * TX;

    const int rowLo = min(max(Y0 - 16, 0), H - WIN_ROWS);
    const int colLo = min(max(X0 - 16, 0), W - WIN_COLS);   // mult of 16

    const int lane = threadIdx.x & 63;
    const int wv   = threadIdx.x >> 6;      // 0..15

    // ---- async staging: issue all global_load_lds, no intervening waits ----
    // LDS dest is chunk-linear (wave-uniform base + lane*16); the 196-float
    // row stride works because 784 B = 49 chunks exactly.
    const float* gwin = image + ((size_t)b * H + rowLo) * (W * C) + colLo * C;
#pragma unroll 1
    for (int j = wv; j * 64 < CHUNKS; j += NWAVES) {
        int ci = j * 64 + lane;
        if (ci >= CHUNKS) ci = CHUNKS - 1;        // tail -> end padding
        const int r = ci / ROW_CHUNKS;            // magic-mul div
        int c = ci - r * ROW_CHUNKS;
        if (c > 47) c = 47;                       // pad chunk: reload data,
                                                  // never read; avoids OOB
        const float* g = gwin + (size_t)r * (W * C) + c * 4;
        __builtin_amdgcn_global_load_lds(
            (const __attribute__((address_space(1))) void*)g,
            (__attribute__((address_space(3))) void*)(win + (size_t)j * 256),
            16, 0, 0);
    }

    // ---- flow loads before barrier: latency hides under staging ----
    vfloat2 f[PX_PER_T];
#pragma unroll
    for (int k = 0; k < PX_PER_T; ++k) {
        const int p   = threadIdx.x + k * NTHREADS;
        const int py  = p >> 5;
        const int pxx = p & 31;
        const size_t pix = ((size_t)b * H + (Y0 + py)) * W + (X0 + pxx);
        f[k] = __builtin_nontemporal_load((const vfloat2*)flow + pix);
    }

    __syncthreads();   // drains vmcnt: staging + flow complete

    // ---- compute: 2 px per thread, gathers served from LDS ----
#pragma unroll
    for (int k = 0; k < PX_PER_T; ++k) {
        const int p   = threadIdx.x + k * NTHREADS;
        const int py  = p >> 5;
        const int pxx = p & 31;
        const int y = Y0 + py;
        const int x = X0 + pxx;
        const size_t pix = ((size_t)b * H + y) * W + x;

        const float qy = (float)y - f[k].x;
        const float qx = (float)x - f[k].y;

        float y0f = floorf(qy);
        float x0f = floorf(qx);
        y0f = fminf(fmaxf(y0f, 0.0f), (float)(H - 2));
        x0f = fminf(fmaxf(x0f, 0.0f), (float)(W - 2));
        const float ay = fminf(fmaxf(qy - y0f, 0.0f), 1.0f);
        const float ax = fminf(fmaxf(qx - x0f, 0.0f), 1.0f);

        const int y0 = (int)y0f;
        const int x0 = (int)x0f;

        float tl0, tl1, tl2, tr0, tr1, tr2, bl0, bl1, bl2, br0, br1, br2;

        const bool inwin = (y0 >= rowLo) & (y0 <= rowLo + WIN_ROWS - 2) &
                           (x0 >= colLo) & (x0 <= colLo + WIN_COLS - 2);
        if (inwin) {
            const float* t = &win[(y0 - rowLo) * WSF + (x0 - colLo) * C];
            tl0 = t[0]; tl1 = t[1]; tl2 = t[2];
            tr0 = t[3]; tr1 = t[4]; tr2 = t[5];
            const float* bo = t + WSF;
            bl0 = bo[0]; bl1 = bo[1]; bl2 = bo[2];
            br0 = bo[3]; br1 = bo[4]; br2 = bo[5];
        } else {
            // rare (~0.4% px): flow beyond halo -> direct global bilinear
            const float* top = image + (((size_t)b * H + y0) * W + x0) * C;
            const float* bot = top + (size_t)W * C;
            const vfloat4 t4 = *(const vfloat4_a4*)top;
            const vfloat2 t2 = *(const vfloat2_a4*)(top + 4);
            const vfloat4 b4 = *(const vfloat4_a4*)bot;
            const vfloat2 b2 = *(const vfloat2_a4*)(bot + 4);
            tl0 = t4.x; tl1 = t4.y; tl2 = t4.z;
            tr0 = t4.w; tr1 = t2.x; tr2 = t2.y;
            bl0 = b4.x; bl1 = b4.y; bl2 = b4.z;
            br0 = b4.w; br1 = b2.x; br2 = b2.y;
        }

        const float tp0 = tl0 + ax * (tr0 - tl0);
        const float tp1 = tl1 + ax * (tr1 - tl1);
        const float tp2 = tl2 + ax * (tr2 - tl2);
        const float bo0 = bl0 + ax * (br0 - bl0);
        const float bo1 = bl1 + ax * (br1 - bl1);
        const float bo2 = bl2 + ax * (br2 - bl2);

        float* o = out + pix * C;
        __builtin_nontemporal_store(tp0 + ay * (bo0 - tp0), &o[0]);
        __builtin_nontemporal_store(tp1 + ay * (bo1 - tp1), &o[1]);
        __builtin_nontemporal_store(tp2 + ay * (bo2 - tp2), &o[2]);
    }
}

extern "C" void kernel_launch(void* const* d_in, const int* in_sizes, int n_in,
                              void* d_out, int out_size, void* d_ws, size_t ws_size,
                              hipStream_t stream) {
    const float* image = (const float*)d_in[0];
    const float* flow  = (const float*)d_in[1];
    float* out = (float*)d_out;

    dim3 grid(B * TILES_PER_B);   // 3072 blocks, 12 rounds of 2/CU
    dim3 block(NTHREADS);
    warp_kernel<<<grid, block, 0, stream>>>(image, flow, out);
}